// Round 3
// baseline (1108.881 us; speedup 1.0000x reference)
//
#include <hip/hip_runtime.h>

#define N_USERS 50000
#define N_ENTITIES 100000
#define N_RELATIONS 16
#define N_EDGES 3200000
#define NNZ 2500000
#define CH 64

#define RPB 64                 // rows per bucket/agg-block
#define NB_E 1563              // ceil(N_ENTITIES/64)
#define NB_U 782               // ceil(N_USERS/64)
#define NBUCKETS (NB_E + NB_U) // 2345
#define UOFF (NB_E * 64)       // 100032: user rows start here (64-aligned)
#define NROWS_PAD (NBUCKETS * 64) // 150080 padded row slots
#define HB 1024                // histogram blocks inside hist_init

__device__ __forceinline__ unsigned short f2bf(float f) {
    unsigned u = __float_as_uint(f);
    u += 0x7FFF + ((u >> 16) & 1);   // round-to-nearest-even
    return (unsigned short)(u >> 16);
}

__device__ __forceinline__ int wave_incl_scan(int v, int lane) {
    int s = v;
    #pragma unroll
    for (int d = 1; d < 64; d <<= 1) {
        int x = __shfl_up(s, d, 64);
        if (lane >= d) s += x;
    }
    return s;
}

// ---------------------------------------------------------------------------
// hist_init: blocks [0,HB) build the per-row histogram with fire-and-forget
// global atomics (no return value -> global_atomic_add, no wait). Blocks
// [HB,..) do the init copy (residuals fp32 + bf16 entity state).
// Row space: entities at [0,100000), users at [UOFF, UOFF+50000).
// ---------------------------------------------------------------------------
__global__ void __launch_bounds__(256)
hist_init_kernel(const float4* __restrict__ user_emb,
                 const float4* __restrict__ entity_emb,
                 ushort4* __restrict__ cur_bf,
                 float4* __restrict__ out_entity,
                 float4* __restrict__ out_user,
                 const int* __restrict__ head, const int* __restrict__ irows,
                 int* __restrict__ cnt) {
    const int blk = blockIdx.x;
    if (blk < HB) {
        const int nth = HB * 256;
        const int tid = blk * 256 + threadIdx.x;
        for (int i = tid; i < N_EDGES; i += nth)
            atomicAdd(&cnt[head[i]], 1);
        for (int i = tid; i < NNZ; i += nth)
            atomicAdd(&cnt[UOFF + irows[i]], 1);
    } else {
        const int ne4 = N_ENTITIES * CH / 4;
        const int nu4 = N_USERS * CH / 4;
        int i = (blk - HB) * 256 + threadIdx.x;
        if (i < ne4) {
            float4 v = entity_emb[i];
            out_entity[i] = v;
            ushort4 bq;
            bq.x = f2bf(v.x); bq.y = f2bf(v.y); bq.z = f2bf(v.z); bq.w = f2bf(v.w);
            cur_bf[i] = bq;
        }
        if (i < nu4) out_user[i] = user_emb[i];
    }
}

// ---------------------------------------------------------------------------
// Hierarchical exclusive scan over the 150080 padded row counts.
// bscan1: one wave per 64-row bucket -> bucket sum.
// bscan2: single block scans the 2345 bucket sums (exclusive).
// bscan3: one wave per bucket rescans its 64 counts -> rowptr + cursor.
// ---------------------------------------------------------------------------
__global__ void __launch_bounds__(256)
bscan1_kernel(const int* __restrict__ cnt, int* __restrict__ bsum) {
    int g = blockIdx.x * 4 + (threadIdx.x >> 6);
    int lane = threadIdx.x & 63;
    if (g >= NBUCKETS) return;
    int v = cnt[g * 64 + lane];
    #pragma unroll
    for (int o = 32; o; o >>= 1) v += __shfl_xor(v, o, 64);
    if (lane == 0) bsum[g] = v;
}

__global__ void __launch_bounds__(512)
bscan2_kernel(const int* __restrict__ bsum, int* __restrict__ bbase) {
    __shared__ int wsums[8];
    __shared__ int carry_s;
    const int t = threadIdx.x, w = t >> 6, lane = t & 63;
    if (t == 0) carry_s = 0;
    __syncthreads();
    for (int base = 0; base < NBUCKETS; base += 512) {
        int i = base + t;
        int v = (i < NBUCKETS) ? bsum[i] : 0;
        int s = wave_incl_scan(v, lane);
        if (lane == 63) wsums[w] = s;
        __syncthreads();
        int carry = carry_s;
        if (w == 0) {
            int ws = (lane < 8) ? wsums[lane] : 0;
            int ss = wave_incl_scan(ws, lane);
            if (lane < 8) wsums[lane] = ss - ws;   // exclusive wave offset
        }
        __syncthreads();
        int excl = s - v + wsums[w] + carry;
        if (i < NBUCKETS) bbase[i] = excl;
        __syncthreads();
        if (t == 511) carry_s = excl + v;
        __syncthreads();
    }
}

__global__ void __launch_bounds__(256)
bscan3_kernel(const int* __restrict__ cnt, const int* __restrict__ bbase,
              int* __restrict__ rowptr, int* __restrict__ cursor) {
    int g = blockIdx.x * 4 + (threadIdx.x >> 6);
    int lane = threadIdx.x & 63;
    if (g >= NBUCKETS) return;
    int v = cnt[g * 64 + lane];
    int s = wave_incl_scan(v, lane);
    int e = bbase[g] + s - v;
    rowptr[g * 64 + lane] = e;
    cursor[g * 64 + lane] = e;
    if (g == NBUCKETS - 1 && lane == 63) rowptr[NROWS_PAD] = e + v;
}

// ---------------------------------------------------------------------------
// scatter: place each edge directly at its final row-sorted CSR slot.
// pos = cursor[row]++ (low contention: ~38 atomics per row counter).
// Payload: KG = { tail | rel<<17 , mask }, user = { col , val }.
// 4-deep manual batching keeps independent atomic->store chains in flight.
// ---------------------------------------------------------------------------
__global__ void __launch_bounds__(256)
scatter_kernel(const int* __restrict__ head, const int* __restrict__ tail,
               const int* __restrict__ type, const float* __restrict__ maskp,
               const int* __restrict__ irows, const int* __restrict__ icols,
               const float* __restrict__ ivals,
               int* __restrict__ cursor, int2* __restrict__ payload) {
    const int nth = gridDim.x * blockDim.x;
    const int tid = blockIdx.x * blockDim.x + threadIdx.x;

    int i = tid;
    for (; i + 3 * nth < N_EDGES; i += 4 * nth) {
        int i0 = i, i1 = i + nth, i2 = i + 2 * nth, i3 = i + 3 * nth;
        int r0 = head[i0], r1 = head[i1], r2 = head[i2], r3 = head[i3];
        int k0 = tail[i0] | ((type[i0] - 1) << 17);
        int k1 = tail[i1] | ((type[i1] - 1) << 17);
        int k2 = tail[i2] | ((type[i2] - 1) << 17);
        int k3 = tail[i3] | ((type[i3] - 1) << 17);
        float m0 = maskp[i0], m1 = maskp[i1], m2 = maskp[i2], m3 = maskp[i3];
        int p0 = atomicAdd(&cursor[r0], 1);
        int p1 = atomicAdd(&cursor[r1], 1);
        int p2 = atomicAdd(&cursor[r2], 1);
        int p3 = atomicAdd(&cursor[r3], 1);
        payload[p0] = make_int2(k0, __float_as_int(m0));
        payload[p1] = make_int2(k1, __float_as_int(m1));
        payload[p2] = make_int2(k2, __float_as_int(m2));
        payload[p3] = make_int2(k3, __float_as_int(m3));
    }
    for (; i < N_EDGES; i += nth) {
        int r = head[i];
        int k = tail[i] | ((type[i] - 1) << 17);
        int p = atomicAdd(&cursor[r], 1);
        payload[p] = make_int2(k, __float_as_int(maskp[i]));
    }

    i = tid;
    for (; i + 3 * nth < NNZ; i += 4 * nth) {
        int i0 = i, i1 = i + nth, i2 = i + 2 * nth, i3 = i + 3 * nth;
        int r0 = UOFF + irows[i0], r1 = UOFF + irows[i1];
        int r2 = UOFF + irows[i2], r3 = UOFF + irows[i3];
        int k0 = icols[i0], k1 = icols[i1], k2 = icols[i2], k3 = icols[i3];
        float v0 = ivals[i0], v1 = ivals[i1], v2 = ivals[i2], v3 = ivals[i3];
        int p0 = atomicAdd(&cursor[r0], 1);
        int p1 = atomicAdd(&cursor[r1], 1);
        int p2 = atomicAdd(&cursor[r2], 1);
        int p3 = atomicAdd(&cursor[r3], 1);
        payload[p0] = make_int2(k0, __float_as_int(v0));
        payload[p1] = make_int2(k1, __float_as_int(v1));
        payload[p2] = make_int2(k2, __float_as_int(v2));
        payload[p3] = make_int2(k3, __float_as_int(v3));
    }
    for (; i < NNZ; i += nth) {
        int r = UOFF + irows[i];
        int p = atomicAdd(&cursor[r], 1);
        payload[p] = make_int2(icols[i], __float_as_int(ivals[i]));
    }
}

// ---------------------------------------------------------------------------
// Aggregation v6: pure-gather over exact CSR. One block (8 waves) per
// 64-row bucket; wave w owns rows 8w..8w+7 (contiguous payload segments).
// Split-wave gather (lanes 0-31 = edge i, 32-63 = edge i+1), one packed
// bf16-pair dword per lane, 8-edge unroll, no main-loop barriers.
// Per-row fused epilogue: merge halves, L2-normalize, residual, next-state.
// ---------------------------------------------------------------------------
__global__ void __launch_bounds__(512)
agg_kernel(const unsigned int* __restrict__ cur32,   // bf16 pairs, 32 dwords/row
           const float* __restrict__ weight,
           const int2* __restrict__ payload, const int* __restrict__ rowptr,
           unsigned short* __restrict__ nxt,
           float* __restrict__ res_e, float* __restrict__ res_u) {
    __shared__ float wlds[N_RELATIONS * CH];   // 4 KB
    __shared__ int   srp[RPB + 1];

    const int b = blockIdx.x;
    const int t = threadIdx.x;
    const int w = t >> 6;        // wave 0..7
    const int lane = t & 63;
    const int h = lane >> 5;     // which edge of the pair this half-wave owns
    const int c = lane & 31;     // dword (channel-pair) index within the row
    const bool is_user = (b < NB_U);
    const int grow0 = is_user ? (UOFF + b * 64) : ((b - NB_U) * 64);
    const int orow0 = is_user ? (b * 64) : ((b - NB_U) * 64);

    if (!is_user)
        for (int i = t; i < N_RELATIONS * CH; i += 512) wlds[i] = weight[i];
    if (t < RPB + 1) srp[t] = rowptr[grow0 + t];
    __syncthreads();
    const float2* __restrict__ wl2 = (const float2*)wlds;

    #pragma unroll
    for (int rr = 0; rr < 8; ++rr) {
        const int row = (w << 3) + rr;
        const int s = srp[row], e = srp[row + 1];
        float x0 = 0.f, x1 = 0.f;
        int i = s;
        if (is_user) {
            for (; i + 7 < e; i += 8) {
                int2 p0 = payload[i + h];
                int2 p1 = payload[i + 2 + h];
                int2 p2 = payload[i + 4 + h];
                int2 p3 = payload[i + 6 + h];
                unsigned q0 = cur32[(size_t)(p0.x & 0x1FFFF) * 32 + c];
                unsigned q1 = cur32[(size_t)(p1.x & 0x1FFFF) * 32 + c];
                unsigned q2 = cur32[(size_t)(p2.x & 0x1FFFF) * 32 + c];
                unsigned q3 = cur32[(size_t)(p3.x & 0x1FFFF) * 32 + c];
                float s0 = __int_as_float(p0.y);
                float s1 = __int_as_float(p1.y);
                float s2 = __int_as_float(p2.y);
                float s3 = __int_as_float(p3.y);
                x0 += __uint_as_float(q0 << 16) * s0;
                x1 += __uint_as_float(q0 & 0xFFFF0000u) * s0;
                x0 += __uint_as_float(q1 << 16) * s1;
                x1 += __uint_as_float(q1 & 0xFFFF0000u) * s1;
                x0 += __uint_as_float(q2 << 16) * s2;
                x1 += __uint_as_float(q2 & 0xFFFF0000u) * s2;
                x0 += __uint_as_float(q3 << 16) * s3;
                x1 += __uint_as_float(q3 & 0xFFFF0000u) * s3;
            }
            for (; i < e; i += 2) {          // 1..7 leftovers, pair-wise
                int idx = i + h;
                bool vld = idx < e;
                int2 p = payload[vld ? idx : i];
                unsigned q = cur32[(size_t)(p.x & 0x1FFFF) * 32 + c];
                float s0 = vld ? __int_as_float(p.y) : 0.f;
                x0 += __uint_as_float(q << 16) * s0;
                x1 += __uint_as_float(q & 0xFFFF0000u) * s0;
            }
        } else {
            for (; i + 7 < e; i += 8) {
                int2 p0 = payload[i + h];
                int2 p1 = payload[i + 2 + h];
                int2 p2 = payload[i + 4 + h];
                int2 p3 = payload[i + 6 + h];
                unsigned q0 = cur32[(size_t)(p0.x & 0x1FFFF) * 32 + c];
                unsigned q1 = cur32[(size_t)(p1.x & 0x1FFFF) * 32 + c];
                unsigned q2 = cur32[(size_t)(p2.x & 0x1FFFF) * 32 + c];
                unsigned q3 = cur32[(size_t)(p3.x & 0x1FFFF) * 32 + c];
                float2 w0 = wl2[((p0.x >> 17) & 15) * 32 + c];
                float2 w1 = wl2[((p1.x >> 17) & 15) * 32 + c];
                float2 w2 = wl2[((p2.x >> 17) & 15) * 32 + c];
                float2 w3 = wl2[((p3.x >> 17) & 15) * 32 + c];
                float s0 = __int_as_float(p0.y);
                float s1 = __int_as_float(p1.y);
                float s2 = __int_as_float(p2.y);
                float s3 = __int_as_float(p3.y);
                x0 += __uint_as_float(q0 << 16) * (s0 * w0.x);
                x1 += __uint_as_float(q0 & 0xFFFF0000u) * (s0 * w0.y);
                x0 += __uint_as_float(q1 << 16) * (s1 * w1.x);
                x1 += __uint_as_float(q1 & 0xFFFF0000u) * (s1 * w1.y);
                x0 += __uint_as_float(q2 << 16) * (s2 * w2.x);
                x1 += __uint_as_float(q2 & 0xFFFF0000u) * (s2 * w2.y);
                x0 += __uint_as_float(q3 << 16) * (s3 * w3.x);
                x1 += __uint_as_float(q3 & 0xFFFF0000u) * (s3 * w3.y);
            }
            for (; i < e; i += 2) {
                int idx = i + h;
                bool vld = idx < e;
                int2 p = payload[vld ? idx : i];
                unsigned q = cur32[(size_t)(p.x & 0x1FFFF) * 32 + c];
                float2 wv = wl2[((p.x >> 17) & 15) * 32 + c];
                float s0 = vld ? __int_as_float(p.y) : 0.f;
                x0 += __uint_as_float(q << 16) * (s0 * wv.x);
                x1 += __uint_as_float(q & 0xFFFF0000u) * (s0 * wv.y);
            }
        }

        // per-row fused epilogue: merge half-waves, L2-normalize, write out
        x0 += __shfl_xor(x0, 32, 64);
        x1 += __shfl_xor(x1, 32, 64);
        float ss = x0 * x0 + x1 * x1;
        #pragma unroll
        for (int o = 16; o; o >>= 1) ss += __shfl_xor(ss, o, 64);
        float inv = 1.f / fmaxf(sqrtf(ss), 1e-12f);
        float y0 = x0 * inv, y1 = x1 * inv;
        if (h == 0) {      // lanes 0-31 hold the complete row; write float2
            int grow = orow0 + row;
            if (is_user) {
                if (grow < N_USERS) {
                    float2* p = (float2*)res_u + (size_t)grow * 32 + c;
                    float2 v = *p; v.x += y0; v.y += y1; *p = v;
                }
            } else {
                if (grow < N_ENTITIES) {
                    ((unsigned*)nxt)[(size_t)grow * 32 + c] =
                        (unsigned)f2bf(y0) | ((unsigned)f2bf(y1) << 16);
                    float2* p = (float2*)res_e + (size_t)grow * 32 + c;
                    float2 v = *p; v.x += y0; v.y += y1; *p = v;
                }
            }
        }
    }
}

extern "C" void kernel_launch(void* const* d_in, const int* in_sizes, int n_in,
                              void* d_out, int out_size, void* d_ws, size_t ws_size,
                              hipStream_t stream) {
    const float* user_emb   = (const float*)d_in[0];
    const float* entity_emb = (const float*)d_in[1];
    const float* weight     = (const float*)d_in[2];
    const float* mask       = (const float*)d_in[3];
    const float* ivals      = (const float*)d_in[4];
    const int*   edge_head  = (const int*)d_in[5];
    const int*   edge_tail  = (const int*)d_in[6];
    const int*   edge_type  = (const int*)d_in[7];
    const int*   irows      = (const int*)d_in[8];
    const int*   icols      = (const int*)d_in[9];

    float* out_entity = (float*)d_out;
    float* out_user   = (float*)d_out + (size_t)N_ENTITIES * CH;

    // ---- workspace layout ----
    unsigned short* curA = (unsigned short*)d_ws;                  // 12.8 MB
    unsigned short* curB = curA + (size_t)N_ENTITIES * CH;         // 12.8 MB
    int2* payload = (int2*)(curB + (size_t)N_ENTITIES * CH);       // 45.6 MB
    int*  cnt     = (int*)(payload + (size_t)(N_EDGES + NNZ));     // 600 KB
    int*  rowptr  = cnt + NROWS_PAD;                               // 600 KB + 4
    int*  cursor  = rowptr + NROWS_PAD + 1;                        // 600 KB
    int*  bsum    = cursor + NROWS_PAD;                            // 9.4 KB
    int*  bbase   = bsum + NBUCKETS;                               // 9.4 KB

    hipMemsetAsync(cnt, 0, (size_t)NROWS_PAD * sizeof(int), stream);

    // ---- histogram + init (overlapped in one grid) ----
    {
        const int init_blocks = (N_ENTITIES * CH / 4 + 255) / 256;   // 6250
        hist_init_kernel<<<HB + init_blocks, 256, 0, stream>>>(
            (const float4*)user_emb, (const float4*)entity_emb,
            (ushort4*)curA, (float4*)out_entity, (float4*)out_user,
            edge_head, irows, cnt);
    }

    // ---- exclusive scan -> rowptr + cursor ----
    bscan1_kernel<<<(NBUCKETS + 3) / 4, 256, 0, stream>>>(cnt, bsum);
    bscan2_kernel<<<1, 512, 0, stream>>>(bsum, bbase);
    bscan3_kernel<<<(NBUCKETS + 3) / 4, 256, 0, stream>>>(cnt, bbase, rowptr, cursor);

    // ---- scatter edges to final row-sorted CSR slots ----
    scatter_kernel<<<2048, 256, 0, stream>>>(
        edge_head, edge_tail, edge_type, mask,
        irows, icols, ivals, cursor, payload);

    // ---- 2 hops, double-buffered bf16 entity state ----
    agg_kernel<<<NBUCKETS, 512, 0, stream>>>(
        (const unsigned int*)curA, weight, payload, rowptr,
        curB, out_entity, out_user);
    agg_kernel<<<NBUCKETS, 512, 0, stream>>>(
        (const unsigned int*)curB, weight, payload, rowptr,
        curA, out_entity, out_user);
}

// Round 4
// 604.712 us; speedup vs baseline: 1.8337x; 1.8337x over previous
//
#include <hip/hip_runtime.h>

#define N_USERS 50000
#define N_ENTITIES 100000
#define N_RELATIONS 16
#define N_EDGES 3200000
#define NNZ 2500000
#define CH 64

#define RPB 64            // destination rows per bucket/block
#define NB_E 1563         // ceil(N_ENTITIES/64)
#define NB_U 782          // ceil(N_USERS/64)
#define CAP_E 2560        // bucket capacity (mean 2047, +11 sigma)
#define CAP_U 3840        // (mean 3197, +11 sigma)

#define BKG 128           // KG binning blocks (long runs -> L2-coalesced writes)
#define BU  96            // user binning blocks
#define BTOT (BKG + BU)

__device__ __forceinline__ unsigned short f2bf(float f) {
    unsigned u = __float_as_uint(f);
    u += 0x7FFF + ((u >> 16) & 1);   // round-to-nearest-even
    return (unsigned short)(u >> 16);
}

// ---------------------------------------------------------------------------
// build: blocks [0,BKG) bin KG edges, [BKG,BTOT) bin user interactions,
// [BTOT,..) do the init copy. FEW blocks + 1024 threads so each
// (block,bucket) reservation is a LONG contiguous run (KG ~16 edges=128B,
// user ~33 edges=266B) and the per-XCD active write-line set (~2.2MB) fits
// L2 -> scattered 8B stores coalesce in L2 instead of thrashing HBM.
// Payload: KG = tail|rel<<17|rowlocal<<21, user = col|rowlocal<<17.
// ---------------------------------------------------------------------------
__global__ void __launch_bounds__(1024)
build_kernel(const float4* __restrict__ user_emb,
             const float4* __restrict__ entity_emb,
             ushort4* __restrict__ cur_bf,
             float4* __restrict__ out_entity,
             float4* __restrict__ out_user,
             const int* __restrict__ head, const int* __restrict__ tail,
             const int* __restrict__ type, const float* __restrict__ maskp,
             const int* __restrict__ irows, const int* __restrict__ icols,
             const float* __restrict__ ivals,
             int* __restrict__ cntE, int2* __restrict__ binE,
             int* __restrict__ cntU, int2* __restrict__ binU) {
    __shared__ int hist[NB_E];
    __shared__ int lbase[NB_E];
    const int blk = blockIdx.x;
    const int t = threadIdx.x;

    if (blk >= BTOT) {
        // ---- init: residuals fp32 + bf16 entity state ----
        const int ne4 = N_ENTITIES * CH / 4;
        const int nu4 = N_USERS * CH / 4;
        int i = (blk - BTOT) * 1024 + t;
        if (i < ne4) {
            float4 v = entity_emb[i];
            out_entity[i] = v;
            ushort4 bq;
            bq.x = f2bf(v.x); bq.y = f2bf(v.y); bq.z = f2bf(v.z); bq.w = f2bf(v.w);
            cur_bf[i] = bq;
        }
        if (i < nu4) out_user[i] = user_emb[i];
        return;
    }

    if (blk < BKG) {
        // ---- KG edges ----
        for (int i = t; i < NB_E; i += 1024) hist[i] = 0;
        __syncthreads();
        const int chunk = (N_EDGES + BKG - 1) / BKG;
        int base = blk * chunk;
        int lim = min(base + chunk, N_EDGES);
        for (int i = base + t; i < lim; i += 1024)
            atomicAdd(&hist[head[i] >> 6], 1);
        __syncthreads();
        for (int i = t; i < NB_E; i += 1024) {
            int c = hist[i];
            lbase[i] = c ? atomicAdd(&cntE[i], c) : 0;
            hist[i] = 0;   // becomes local cursor
        }
        __syncthreads();
        for (int i = base + t; i < lim; i += 1024) {
            int h = head[i];
            int b = h >> 6;
            int loc = lbase[b] + atomicAdd(&hist[b], 1);
            if (loc < CAP_E)
                binE[(size_t)b * CAP_E + loc] =
                    make_int2(tail[i] | ((type[i] - 1) << 17) | ((h & 63) << 21),
                              __float_as_int(maskp[i]));
        }
    } else {
        // ---- user interactions ----
        const int ub = blk - BKG;
        for (int i = t; i < NB_U; i += 1024) hist[i] = 0;
        __syncthreads();
        const int chunk = (NNZ + BU - 1) / BU;
        int base = ub * chunk;
        int lim = min(base + chunk, NNZ);
        for (int i = base + t; i < lim; i += 1024)
            atomicAdd(&hist[irows[i] >> 6], 1);
        __syncthreads();
        for (int i = t; i < NB_U; i += 1024) {
            int c = hist[i];
            lbase[i] = c ? atomicAdd(&cntU[i], c) : 0;
            hist[i] = 0;
        }
        __syncthreads();
        for (int i = base + t; i < lim; i += 1024) {
            int r = irows[i];
            int b = r >> 6;
            int loc = lbase[b] + atomicAdd(&hist[b], 1);
            if (loc < CAP_U)
                binU[(size_t)b * CAP_U + loc] =
                    make_int2(icols[i] | ((r & 63) << 17), __float_as_int(ivals[i]));
        }
    }
}

// ---------------------------------------------------------------------------
// One-shot bucket sort: counting-sort each bucket by rowlocal IN PLACE
// (whole bucket staged in LDS, <=3840 entries * 8B * 2 buffers = 60KB),
// emit per-bucket rowptr[65]. Paid once; both agg hops then consume
// row-contiguous segments with zero sort/barrier work.
// ---------------------------------------------------------------------------
__global__ void __launch_bounds__(512)
sort_kernel(int2* __restrict__ binE, const int* __restrict__ cntE,
            int2* __restrict__ binU, const int* __restrict__ cntU,
            int* __restrict__ rowptr) {
    __shared__ int2 buf[CAP_U];       // 30720 B
    __shared__ int2 sbuf[CAP_U];      // 30720 B
    __shared__ int  hist[RPB];
    __shared__ int  offs[RPB + 1];

    const int b = blockIdx.x;
    const int t = threadIdx.x;
    const bool is_user = (b < NB_U);
    const int eb = b - NB_U;
    int2* __restrict__ bin = is_user ? (binU + (size_t)b * CAP_U)
                                     : (binE + (size_t)eb * CAP_E);
    const int cnt = is_user ? min(cntU[b], CAP_U) : min(cntE[eb], CAP_E);
    const int rsh = is_user ? 17 : 21;

    if (t < RPB) hist[t] = 0;
    for (int i = t; i < cnt; i += 512) buf[i] = bin[i];
    __syncthreads();
    for (int i = t; i < cnt; i += 512)
        atomicAdd(&hist[(buf[i].x >> rsh) & 63], 1);
    __syncthreads();
    if (t < 64) {        // wave 0: exclusive scan of 64 counts
        int v = hist[t];
        int s = v;
        #pragma unroll
        for (int d = 1; d < 64; d <<= 1) {
            int nb = __shfl_up(s, d, 64);
            if (t >= d) s += nb;
        }
        offs[t] = s - v;
        if (t == 63) offs[64] = s;
    }
    __syncthreads();
    if (t < RPB) hist[t] = 0;        // becomes cursor
    __syncthreads();
    for (int i = t; i < cnt; i += 512) {
        int2 p = buf[i];
        int r = (p.x >> rsh) & 63;
        int k = atomicAdd(&hist[r], 1);
        sbuf[offs[r] + k] = p;
    }
    __syncthreads();
    for (int i = t; i < cnt; i += 512) bin[i] = sbuf[i];   // coalesced writeback
    if (t <= 64) rowptr[b * 65 + t] = offs[t];
}

// ---------------------------------------------------------------------------
// Aggregation: pure-gather. One block (512 thr = 8 waves) per bucket;
// wave w owns rows 8w..8w+7, each row a contiguous payload segment
// [rp[row], rp[row+1]) in the pre-sorted bin. No LDS staging, no barriers
// in the main loop. Split-wave gather: lanes 0-31 = edge i, lanes 32-63 =
// edge i+1; each lane loads one dword (2 packed bf16). 8-edge unroll keeps
// 4 independent payload->gather chains in flight. Per-row fused epilogue.
// ---------------------------------------------------------------------------
__global__ void __launch_bounds__(512)
agg_kernel(const unsigned int* __restrict__ cur32,   // bf16 pairs, 32 dwords/row
           const float* __restrict__ weight,
           const int2* __restrict__ binE, const int2* __restrict__ binU,
           const int* __restrict__ rowptr,
           unsigned short* __restrict__ nxt,
           float* __restrict__ res_e, float* __restrict__ res_u) {
    __shared__ float wlds[N_RELATIONS * CH];   // 4 KB

    const int b = blockIdx.x;
    const int t = threadIdx.x;
    const int w = t >> 6;        // wave 0..7
    const int lane = t & 63;
    const int h = lane >> 5;     // which edge of the pair this half-wave owns
    const int c = lane & 31;     // dword (channel-pair) index within the row
    const bool is_user = (b < NB_U);
    const int eb = b - NB_U;
    const int2* __restrict__ bin = is_user ? (binU + (size_t)b * CAP_U)
                                           : (binE + (size_t)eb * CAP_E);
    const int* __restrict__ rp = rowptr + b * 65;

    if (!is_user)
        for (int i = t; i < N_RELATIONS * CH; i += 512) wlds[i] = weight[i];
    __syncthreads();
    const float2* __restrict__ wl2 = (const float2*)wlds;

    #pragma unroll
    for (int rr = 0; rr < 8; ++rr) {
        const int row = (w << 3) + rr;
        const int s = rp[row], e = rp[row + 1];
        float x0 = 0.f, x1 = 0.f;
        int i = s;
        if (is_user) {
            for (; i + 7 < e; i += 8) {
                int2 p0 = bin[i + h];
                int2 p1 = bin[i + 2 + h];
                int2 p2 = bin[i + 4 + h];
                int2 p3 = bin[i + 6 + h];
                unsigned q0 = cur32[(size_t)(p0.x & 0x1FFFF) * 32 + c];
                unsigned q1 = cur32[(size_t)(p1.x & 0x1FFFF) * 32 + c];
                unsigned q2 = cur32[(size_t)(p2.x & 0x1FFFF) * 32 + c];
                unsigned q3 = cur32[(size_t)(p3.x & 0x1FFFF) * 32 + c];
                float s0 = __int_as_float(p0.y);
                float s1 = __int_as_float(p1.y);
                float s2 = __int_as_float(p2.y);
                float s3 = __int_as_float(p3.y);
                x0 += __uint_as_float(q0 << 16) * s0;
                x1 += __uint_as_float(q0 & 0xFFFF0000u) * s0;
                x0 += __uint_as_float(q1 << 16) * s1;
                x1 += __uint_as_float(q1 & 0xFFFF0000u) * s1;
                x0 += __uint_as_float(q2 << 16) * s2;
                x1 += __uint_as_float(q2 & 0xFFFF0000u) * s2;
                x0 += __uint_as_float(q3 << 16) * s3;
                x1 += __uint_as_float(q3 & 0xFFFF0000u) * s3;
            }
            for (; i < e; i += 2) {          // 1..7 leftovers, pair-wise
                int idx = i + h;
                bool vld = idx < e;
                int2 p = bin[vld ? idx : i];
                unsigned q = cur32[(size_t)(p.x & 0x1FFFF) * 32 + c];
                float s0 = vld ? __int_as_float(p.y) : 0.f;
                x0 += __uint_as_float(q << 16) * s0;
                x1 += __uint_as_float(q & 0xFFFF0000u) * s0;
            }
        } else {
            for (; i + 7 < e; i += 8) {
                int2 p0 = bin[i + h];
                int2 p1 = bin[i + 2 + h];
                int2 p2 = bin[i + 4 + h];
                int2 p3 = bin[i + 6 + h];
                unsigned q0 = cur32[(size_t)(p0.x & 0x1FFFF) * 32 + c];
                unsigned q1 = cur32[(size_t)(p1.x & 0x1FFFF) * 32 + c];
                unsigned q2 = cur32[(size_t)(p2.x & 0x1FFFF) * 32 + c];
                unsigned q3 = cur32[(size_t)(p3.x & 0x1FFFF) * 32 + c];
                float2 w0 = wl2[((p0.x >> 17) & 15) * 32 + c];
                float2 w1 = wl2[((p1.x >> 17) & 15) * 32 + c];
                float2 w2 = wl2[((p2.x >> 17) & 15) * 32 + c];
                float2 w3 = wl2[((p3.x >> 17) & 15) * 32 + c];
                float s0 = __int_as_float(p0.y);
                float s1 = __int_as_float(p1.y);
                float s2 = __int_as_float(p2.y);
                float s3 = __int_as_float(p3.y);
                x0 += __uint_as_float(q0 << 16) * (s0 * w0.x);
                x1 += __uint_as_float(q0 & 0xFFFF0000u) * (s0 * w0.y);
                x0 += __uint_as_float(q1 << 16) * (s1 * w1.x);
                x1 += __uint_as_float(q1 & 0xFFFF0000u) * (s1 * w1.y);
                x0 += __uint_as_float(q2 << 16) * (s2 * w2.x);
                x1 += __uint_as_float(q2 & 0xFFFF0000u) * (s2 * w2.y);
                x0 += __uint_as_float(q3 << 16) * (s3 * w3.x);
                x1 += __uint_as_float(q3 & 0xFFFF0000u) * (s3 * w3.y);
            }
            for (; i < e; i += 2) {
                int idx = i + h;
                bool vld = idx < e;
                int2 p = bin[vld ? idx : i];
                unsigned q = cur32[(size_t)(p.x & 0x1FFFF) * 32 + c];
                float2 wv = wl2[((p.x >> 17) & 15) * 32 + c];
                float s0 = vld ? __int_as_float(p.y) : 0.f;
                x0 += __uint_as_float(q << 16) * (s0 * wv.x);
                x1 += __uint_as_float(q & 0xFFFF0000u) * (s0 * wv.y);
            }
        }

        // per-row fused epilogue: merge half-waves, L2-normalize, write out
        x0 += __shfl_xor(x0, 32, 64);
        x1 += __shfl_xor(x1, 32, 64);
        float ss = x0 * x0 + x1 * x1;
        #pragma unroll
        for (int o = 16; o; o >>= 1) ss += __shfl_xor(ss, o, 64);
        float inv = 1.f / fmaxf(sqrtf(ss), 1e-12f);
        float y0 = x0 * inv, y1 = x1 * inv;
        if (h == 0) {      // lanes 0-31 hold the complete row; write float2
            if (is_user) {
                int grow = b * RPB + row;
                if (grow < N_USERS) {
                    float2* p = (float2*)res_u + (size_t)grow * 32 + c;
                    float2 v = *p; v.x += y0; v.y += y1; *p = v;
                }
            } else {
                int grow = eb * RPB + row;
                if (grow < N_ENTITIES) {
                    ((unsigned*)nxt)[(size_t)grow * 32 + c] =
                        (unsigned)f2bf(y0) | ((unsigned)f2bf(y1) << 16);
                    float2* p = (float2*)res_e + (size_t)grow * 32 + c;
                    float2 v = *p; v.x += y0; v.y += y1; *p = v;
                }
            }
        }
    }
}

extern "C" void kernel_launch(void* const* d_in, const int* in_sizes, int n_in,
                              void* d_out, int out_size, void* d_ws, size_t ws_size,
                              hipStream_t stream) {
    const float* user_emb   = (const float*)d_in[0];
    const float* entity_emb = (const float*)d_in[1];
    const float* weight     = (const float*)d_in[2];
    const float* mask       = (const float*)d_in[3];
    const float* ivals      = (const float*)d_in[4];
    const int*   edge_head  = (const int*)d_in[5];
    const int*   edge_tail  = (const int*)d_in[6];
    const int*   edge_type  = (const int*)d_in[7];
    const int*   irows      = (const int*)d_in[8];
    const int*   icols      = (const int*)d_in[9];

    float* out_entity = (float*)d_out;
    float* out_user   = (float*)d_out + (size_t)N_ENTITIES * CH;

    // ---- workspace layout ----
    unsigned short* curA = (unsigned short*)d_ws;                 // 12.8 MB
    unsigned short* curB = curA + (size_t)N_ENTITIES * CH;        // 12.8 MB
    int2* binE = (int2*)(curB + (size_t)N_ENTITIES * CH);         // 32 MB
    int2* binU = binE + (size_t)NB_E * CAP_E;                     // 24 MB
    int*  cntE = (int*)(binU + (size_t)NB_U * CAP_U);             // 1563
    int*  cntU = cntE + NB_E;                                     // 782
    int*  rowptr = cntU + NB_U;                                   // 2345*65 = 0.61 MB

    // ---- build: binning (both graphs) + init, one overlapped launch ----
    hipMemsetAsync(cntE, 0, (size_t)(NB_E + NB_U) * sizeof(int), stream);
    {
        const int init_blocks = (N_ENTITIES * CH / 4 + 1023) / 1024;   // 1563
        build_kernel<<<BTOT + init_blocks, 1024, 0, stream>>>(
            (const float4*)user_emb, (const float4*)entity_emb,
            (ushort4*)curA, (float4*)out_entity, (float4*)out_user,
            edge_head, edge_tail, edge_type, mask,
            irows, icols, ivals,
            cntE, binE, cntU, binU);
    }

    // ---- one-shot in-place bucket sort + rowptr ----
    sort_kernel<<<NB_U + NB_E, 512, 0, stream>>>(binE, cntE, binU, cntU, rowptr);

    // ---- 2 hops, double-buffered bf16 entity state ----
    agg_kernel<<<NB_U + NB_E, 512, 0, stream>>>(
        (const unsigned int*)curA, weight, binE, binU, rowptr,
        curB, out_entity, out_user);
    agg_kernel<<<NB_U + NB_E, 512, 0, stream>>>(
        (const unsigned int*)curB, weight, binE, binU, rowptr,
        curA, out_entity, out_user);
}

// Round 5
// 550.678 us; speedup vs baseline: 2.0137x; 1.0981x over previous
//
#include <hip/hip_runtime.h>

#define N_USERS 50000
#define N_ENTITIES 100000
#define N_RELATIONS 16
#define N_EDGES 3200000
#define NNZ 2500000
#define CH 64

#define RPB 64            // destination rows per bucket/block
#define NB_E 1563         // ceil(N_ENTITIES/64)
#define NB_U 782          // ceil(N_USERS/64)
#define CAP_E 2560        // bucket capacity (mean 2047, +11 sigma)
#define CAP_U 3840        // (mean 3197, +11 sigma)

#define BKG 128           // KG binning blocks (long runs -> L2-coalesced writes)
#define BU  96            // user binning blocks
#define BTOT (BKG + BU)

__device__ __forceinline__ unsigned short f2bf(float f) {
    unsigned u = __float_as_uint(f);
    u += 0x7FFF + ((u >> 16) & 1);   // round-to-nearest-even
    return (unsigned short)(u >> 16);
}

// ---------------------------------------------------------------------------
// build: blocks [0,BKG) bin KG edges, [BKG,BTOT) bin user interactions,
// [BTOT,..) init copy. Few blocks + 1024 threads so each (block,bucket)
// reservation is a LONG contiguous run and the active write-line set fits
// per-XCD L2 (scattered 8B stores coalesce in L2). Scatter loops unrolled
// 4x with independent load->ds_add_rtn->store chains for MLP.
// ---------------------------------------------------------------------------
__global__ void __launch_bounds__(1024)
build_kernel(const float4* __restrict__ user_emb,
             const float4* __restrict__ entity_emb,
             ushort4* __restrict__ cur_bf,
             float4* __restrict__ out_entity,
             float4* __restrict__ out_user,
             const int* __restrict__ head, const int* __restrict__ tail,
             const int* __restrict__ type, const float* __restrict__ maskp,
             const int* __restrict__ irows, const int* __restrict__ icols,
             const float* __restrict__ ivals,
             int* __restrict__ cntE, int2* __restrict__ binE,
             int* __restrict__ cntU, int2* __restrict__ binU) {
    __shared__ int hist[NB_E];
    __shared__ int lbase[NB_E];
    const int blk = blockIdx.x;
    const int t = threadIdx.x;

    if (blk >= BTOT) {
        // ---- init: residuals fp32 + bf16 entity state ----
        const int ne4 = N_ENTITIES * CH / 4;
        const int nu4 = N_USERS * CH / 4;
        int i = (blk - BTOT) * 1024 + t;
        if (i < ne4) {
            float4 v = entity_emb[i];
            out_entity[i] = v;
            ushort4 bq;
            bq.x = f2bf(v.x); bq.y = f2bf(v.y); bq.z = f2bf(v.z); bq.w = f2bf(v.w);
            cur_bf[i] = bq;
        }
        if (i < nu4) out_user[i] = user_emb[i];
        return;
    }

    if (blk < BKG) {
        // ---- KG edges: payload tail|rel<<17|rowlocal<<21 ----
        for (int i = t; i < NB_E; i += 1024) hist[i] = 0;
        __syncthreads();
        const int chunk = (N_EDGES + BKG - 1) / BKG;
        int base = blk * chunk;
        int lim = min(base + chunk, N_EDGES);
        for (int i = base + t; i < lim; i += 1024)
            atomicAdd(&hist[head[i] >> 6], 1);
        __syncthreads();
        for (int i = t; i < NB_E; i += 1024) {
            int c = hist[i];
            lbase[i] = c ? atomicAdd(&cntE[i], c) : 0;
            hist[i] = 0;   // becomes local cursor
        }
        __syncthreads();
        int i = base + t;
        for (; i + 3072 < lim; i += 4096) {
            int i0 = i, i1 = i + 1024, i2 = i + 2048, i3 = i + 3072;
            int h0 = head[i0], h1 = head[i1], h2 = head[i2], h3 = head[i3];
            int k0 = tail[i0] | ((type[i0] - 1) << 17) | ((h0 & 63) << 21);
            int k1 = tail[i1] | ((type[i1] - 1) << 17) | ((h1 & 63) << 21);
            int k2 = tail[i2] | ((type[i2] - 1) << 17) | ((h2 & 63) << 21);
            int k3 = tail[i3] | ((type[i3] - 1) << 17) | ((h3 & 63) << 21);
            float m0 = maskp[i0], m1 = maskp[i1], m2 = maskp[i2], m3 = maskp[i3];
            int b0 = h0 >> 6, b1 = h1 >> 6, b2 = h2 >> 6, b3 = h3 >> 6;
            int l0 = lbase[b0] + atomicAdd(&hist[b0], 1);
            int l1 = lbase[b1] + atomicAdd(&hist[b1], 1);
            int l2 = lbase[b2] + atomicAdd(&hist[b2], 1);
            int l3 = lbase[b3] + atomicAdd(&hist[b3], 1);
            if (l0 < CAP_E) binE[(size_t)b0 * CAP_E + l0] = make_int2(k0, __float_as_int(m0));
            if (l1 < CAP_E) binE[(size_t)b1 * CAP_E + l1] = make_int2(k1, __float_as_int(m1));
            if (l2 < CAP_E) binE[(size_t)b2 * CAP_E + l2] = make_int2(k2, __float_as_int(m2));
            if (l3 < CAP_E) binE[(size_t)b3 * CAP_E + l3] = make_int2(k3, __float_as_int(m3));
        }
        for (; i < lim; i += 1024) {
            int h = head[i];
            int b = h >> 6;
            int loc = lbase[b] + atomicAdd(&hist[b], 1);
            if (loc < CAP_E)
                binE[(size_t)b * CAP_E + loc] =
                    make_int2(tail[i] | ((type[i] - 1) << 17) | ((h & 63) << 21),
                              __float_as_int(maskp[i]));
        }
    } else {
        // ---- user interactions: payload col|rowlocal<<17 ----
        const int ub = blk - BKG;
        for (int i = t; i < NB_U; i += 1024) hist[i] = 0;
        __syncthreads();
        const int chunk = (NNZ + BU - 1) / BU;
        int base = ub * chunk;
        int lim = min(base + chunk, NNZ);
        for (int i = base + t; i < lim; i += 1024)
            atomicAdd(&hist[irows[i] >> 6], 1);
        __syncthreads();
        for (int i = t; i < NB_U; i += 1024) {
            int c = hist[i];
            lbase[i] = c ? atomicAdd(&cntU[i], c) : 0;
            hist[i] = 0;
        }
        __syncthreads();
        int i = base + t;
        for (; i + 3072 < lim; i += 4096) {
            int i0 = i, i1 = i + 1024, i2 = i + 2048, i3 = i + 3072;
            int r0 = irows[i0], r1 = irows[i1], r2 = irows[i2], r3 = irows[i3];
            int k0 = icols[i0] | ((r0 & 63) << 17);
            int k1 = icols[i1] | ((r1 & 63) << 17);
            int k2 = icols[i2] | ((r2 & 63) << 17);
            int k3 = icols[i3] | ((r3 & 63) << 17);
            float v0 = ivals[i0], v1 = ivals[i1], v2 = ivals[i2], v3 = ivals[i3];
            int b0 = r0 >> 6, b1 = r1 >> 6, b2 = r2 >> 6, b3 = r3 >> 6;
            int l0 = lbase[b0] + atomicAdd(&hist[b0], 1);
            int l1 = lbase[b1] + atomicAdd(&hist[b1], 1);
            int l2 = lbase[b2] + atomicAdd(&hist[b2], 1);
            int l3 = lbase[b3] + atomicAdd(&hist[b3], 1);
            if (l0 < CAP_U) binU[(size_t)b0 * CAP_U + l0] = make_int2(k0, __float_as_int(v0));
            if (l1 < CAP_U) binU[(size_t)b1 * CAP_U + l1] = make_int2(k1, __float_as_int(v1));
            if (l2 < CAP_U) binU[(size_t)b2 * CAP_U + l2] = make_int2(k2, __float_as_int(v2));
            if (l3 < CAP_U) binU[(size_t)b3 * CAP_U + l3] = make_int2(k3, __float_as_int(v3));
        }
        for (; i < lim; i += 1024) {
            int r = irows[i];
            int b = r >> 6;
            int loc = lbase[b] + atomicAdd(&hist[b], 1);
            if (loc < CAP_U)
                binU[(size_t)b * CAP_U + loc] =
                    make_int2(icols[i] | ((r & 63) << 17), __float_as_int(ivals[i]));
        }
    }
}

// ---------------------------------------------------------------------------
// One-shot bucket sort: counting-sort each bucket by rowlocal IN PLACE
// (whole bucket staged in LDS), emit per-bucket rowptr[65]. Paid once;
// both agg hops then consume row-contiguous segments.
// ---------------------------------------------------------------------------
__global__ void __launch_bounds__(512)
sort_kernel(int2* __restrict__ binE, const int* __restrict__ cntE,
            int2* __restrict__ binU, const int* __restrict__ cntU,
            int* __restrict__ rowptr) {
    __shared__ int2 buf[CAP_U];       // 30720 B
    __shared__ int2 sbuf[CAP_U];      // 30720 B
    __shared__ int  hist[RPB];
    __shared__ int  offs[RPB + 1];

    const int b = blockIdx.x;
    const int t = threadIdx.x;
    const bool is_user = (b < NB_U);
    const int eb = b - NB_U;
    int2* __restrict__ bin = is_user ? (binU + (size_t)b * CAP_U)
                                     : (binE + (size_t)eb * CAP_E);
    const int cnt = is_user ? min(cntU[b], CAP_U) : min(cntE[eb], CAP_E);
    const int rsh = is_user ? 17 : 21;

    if (t < RPB) hist[t] = 0;
    for (int i = t; i < cnt; i += 512) buf[i] = bin[i];
    __syncthreads();
    for (int i = t; i < cnt; i += 512)
        atomicAdd(&hist[(buf[i].x >> rsh) & 63], 1);
    __syncthreads();
    if (t < 64) {        // wave 0: exclusive scan of 64 counts
        int v = hist[t];
        int s = v;
        #pragma unroll
        for (int d = 1; d < 64; d <<= 1) {
            int nb = __shfl_up(s, d, 64);
            if (t >= d) s += nb;
        }
        offs[t] = s - v;
        if (t == 63) offs[64] = s;
    }
    __syncthreads();
    if (t < RPB) hist[t] = 0;        // becomes cursor
    __syncthreads();
    for (int i = t; i < cnt; i += 512) {
        int2 p = buf[i];
        int r = (p.x >> rsh) & 63;
        int k = atomicAdd(&hist[r], 1);
        sbuf[offs[r] + k] = p;
    }
    __syncthreads();
    for (int i = t; i < cnt; i += 512) bin[i] = sbuf[i];   // coalesced writeback
    if (t <= 64) rowptr[b * 65 + t] = offs[t];
}

// ---------------------------------------------------------------------------
// Aggregation v7: pure-gather, 4-channel lanes. One block (8 waves) per
// bucket; wave w owns rows 8w..8w+7. Wave = 4 groups of 16 lanes; group g
// processes edge i+g, each lane loads uint2 (4 packed bf16 channels).
// Per 8 edges: 2 payload + 2 gather VMEM + 2 ds_read_b128 (vs 4/4/4 with
// 2-channel lanes) — fewer instructions, 2x bytes per load in flight.
// Epilogue merges the 4 groups (shfl_xor 16,32), L2-normalizes, writes
// float4 residual + packed uint2 next-state from lanes 0-15.
// ---------------------------------------------------------------------------
__global__ void __launch_bounds__(512)
agg_kernel(const uint2* __restrict__ cur64,    // bf16 quads, 16 uint2/row
           const float* __restrict__ weight,
           const int2* __restrict__ binE, const int2* __restrict__ binU,
           const int* __restrict__ rowptr,
           unsigned short* __restrict__ nxt,
           float* __restrict__ res_e, float* __restrict__ res_u) {
    __shared__ float4 wl4[N_RELATIONS * 16];   // 4 KB
    __shared__ int    srp[RPB + 1];

    const int b = blockIdx.x;
    const int t = threadIdx.x;
    const int w = t >> 6;        // wave 0..7
    const int lane = t & 63;
    const int g = lane >> 4;     // edge-group 0..3
    const int c2 = lane & 15;    // uint2 index within row (4 channels)
    const bool is_user = (b < NB_U);
    const int eb = b - NB_U;
    const int2* __restrict__ bin = is_user ? (binU + (size_t)b * CAP_U)
                                           : (binE + (size_t)eb * CAP_E);

    if (!is_user)
        for (int i = t; i < N_RELATIONS * 16; i += 512)
            wl4[i] = ((const float4*)weight)[i];
    if (t < RPB + 1) srp[t] = rowptr[b * 65 + t];
    __syncthreads();

    #pragma unroll
    for (int rr = 0; rr < 8; ++rr) {
        const int row = (w << 3) + rr;
        const int s = srp[row], e = srp[row + 1];
        float x0 = 0.f, x1 = 0.f, x2 = 0.f, x3 = 0.f;
        int i = s;
        if (is_user) {
            for (; i + 7 < e; i += 8) {
                int2 pa = bin[i + g];
                int2 pb = bin[i + 4 + g];
                uint2 qa = cur64[(size_t)(pa.x & 0x1FFFF) * 16 + c2];
                uint2 qb = cur64[(size_t)(pb.x & 0x1FFFF) * 16 + c2];
                float sa = __int_as_float(pa.y);
                float sb = __int_as_float(pb.y);
                x0 += __uint_as_float(qa.x << 16) * sa;
                x1 += __uint_as_float(qa.x & 0xFFFF0000u) * sa;
                x2 += __uint_as_float(qa.y << 16) * sa;
                x3 += __uint_as_float(qa.y & 0xFFFF0000u) * sa;
                x0 += __uint_as_float(qb.x << 16) * sb;
                x1 += __uint_as_float(qb.x & 0xFFFF0000u) * sb;
                x2 += __uint_as_float(qb.y << 16) * sb;
                x3 += __uint_as_float(qb.y & 0xFFFF0000u) * sb;
            }
            for (; i < e; i += 4) {          // masked 4-edge tail
                int idx = i + g;
                bool vld = idx < e;
                int2 p = bin[vld ? idx : i];
                uint2 q = cur64[(size_t)(p.x & 0x1FFFF) * 16 + c2];
                float sv = vld ? __int_as_float(p.y) : 0.f;
                x0 += __uint_as_float(q.x << 16) * sv;
                x1 += __uint_as_float(q.x & 0xFFFF0000u) * sv;
                x2 += __uint_as_float(q.y << 16) * sv;
                x3 += __uint_as_float(q.y & 0xFFFF0000u) * sv;
            }
        } else {
            for (; i + 7 < e; i += 8) {
                int2 pa = bin[i + g];
                int2 pb = bin[i + 4 + g];
                uint2 qa = cur64[(size_t)(pa.x & 0x1FFFF) * 16 + c2];
                uint2 qb = cur64[(size_t)(pb.x & 0x1FFFF) * 16 + c2];
                float4 wa = wl4[((pa.x >> 17) & 15) * 16 + c2];
                float4 wb = wl4[((pb.x >> 17) & 15) * 16 + c2];
                float sa = __int_as_float(pa.y);
                float sb = __int_as_float(pb.y);
                x0 += __uint_as_float(qa.x << 16) * (sa * wa.x);
                x1 += __uint_as_float(qa.x & 0xFFFF0000u) * (sa * wa.y);
                x2 += __uint_as_float(qa.y << 16) * (sa * wa.z);
                x3 += __uint_as_float(qa.y & 0xFFFF0000u) * (sa * wa.w);
                x0 += __uint_as_float(qb.x << 16) * (sb * wb.x);
                x1 += __uint_as_float(qb.x & 0xFFFF0000u) * (sb * wb.y);
                x2 += __uint_as_float(qb.y << 16) * (sb * wb.z);
                x3 += __uint_as_float(qb.y & 0xFFFF0000u) * (sb * wb.w);
            }
            for (; i < e; i += 4) {
                int idx = i + g;
                bool vld = idx < e;
                int2 p = bin[vld ? idx : i];
                uint2 q = cur64[(size_t)(p.x & 0x1FFFF) * 16 + c2];
                float4 wv = wl4[((p.x >> 17) & 15) * 16 + c2];
                float sv = vld ? __int_as_float(p.y) : 0.f;
                x0 += __uint_as_float(q.x << 16) * (sv * wv.x);
                x1 += __uint_as_float(q.x & 0xFFFF0000u) * (sv * wv.y);
                x2 += __uint_as_float(q.y << 16) * (sv * wv.z);
                x3 += __uint_as_float(q.y & 0xFFFF0000u) * (sv * wv.w);
            }
        }

        // merge the 4 edge-groups
        x0 += __shfl_xor(x0, 16, 64); x0 += __shfl_xor(x0, 32, 64);
        x1 += __shfl_xor(x1, 16, 64); x1 += __shfl_xor(x1, 32, 64);
        x2 += __shfl_xor(x2, 16, 64); x2 += __shfl_xor(x2, 32, 64);
        x3 += __shfl_xor(x3, 16, 64); x3 += __shfl_xor(x3, 32, 64);
        float ss = x0 * x0 + x1 * x1 + x2 * x2 + x3 * x3;
        #pragma unroll
        for (int o = 8; o; o >>= 1) ss += __shfl_xor(ss, o, 64);
        float inv = 1.f / fmaxf(sqrtf(ss), 1e-12f);
        float y0 = x0 * inv, y1 = x1 * inv, y2 = x2 * inv, y3 = x3 * inv;
        if (g == 0) {    // lanes 0-15 hold the complete row; 16B stores
            if (is_user) {
                int grow = b * RPB + row;
                if (grow < N_USERS) {
                    float4* p = (float4*)res_u + (size_t)grow * 16 + c2;
                    float4 v = *p;
                    v.x += y0; v.y += y1; v.z += y2; v.w += y3;
                    *p = v;
                }
            } else {
                int grow = eb * RPB + row;
                if (grow < N_ENTITIES) {
                    uint2 pk;
                    pk.x = (unsigned)f2bf(y0) | ((unsigned)f2bf(y1) << 16);
                    pk.y = (unsigned)f2bf(y2) | ((unsigned)f2bf(y3) << 16);
                    ((uint2*)nxt)[(size_t)grow * 16 + c2] = pk;
                    float4* p = (float4*)res_e + (size_t)grow * 16 + c2;
                    float4 v = *p;
                    v.x += y0; v.y += y1; v.z += y2; v.w += y3;
                    *p = v;
                }
            }
        }
    }
}

extern "C" void kernel_launch(void* const* d_in, const int* in_sizes, int n_in,
                              void* d_out, int out_size, void* d_ws, size_t ws_size,
                              hipStream_t stream) {
    const float* user_emb   = (const float*)d_in[0];
    const float* entity_emb = (const float*)d_in[1];
    const float* weight     = (const float*)d_in[2];
    const float* mask       = (const float*)d_in[3];
    const float* ivals      = (const float*)d_in[4];
    const int*   edge_head  = (const int*)d_in[5];
    const int*   edge_tail  = (const int*)d_in[6];
    const int*   edge_type  = (const int*)d_in[7];
    const int*   irows      = (const int*)d_in[8];
    const int*   icols      = (const int*)d_in[9];

    float* out_entity = (float*)d_out;
    float* out_user   = (float*)d_out + (size_t)N_ENTITIES * CH;

    // ---- workspace layout ----
    unsigned short* curA = (unsigned short*)d_ws;                 // 12.8 MB
    unsigned short* curB = curA + (size_t)N_ENTITIES * CH;        // 12.8 MB
    int2* binE = (int2*)(curB + (size_t)N_ENTITIES * CH);         // 32 MB
    int2* binU = binE + (size_t)NB_E * CAP_E;                     // 24 MB
    int*  cntE = (int*)(binU + (size_t)NB_U * CAP_U);             // 1563
    int*  cntU = cntE + NB_E;                                     // 782
    int*  rowptr = cntU + NB_U;                                   // 2345*65

    // ---- build: binning (both graphs) + init, one overlapped launch ----
    hipMemsetAsync(cntE, 0, (size_t)(NB_E + NB_U) * sizeof(int), stream);
    {
        const int init_blocks = (N_ENTITIES * CH / 4 + 1023) / 1024;   // 1563
        build_kernel<<<BTOT + init_blocks, 1024, 0, stream>>>(
            (const float4*)user_emb, (const float4*)entity_emb,
            (ushort4*)curA, (float4*)out_entity, (float4*)out_user,
            edge_head, edge_tail, edge_type, mask,
            irows, icols, ivals,
            cntE, binE, cntU, binU);
    }

    // ---- one-shot in-place bucket sort + rowptr ----
    sort_kernel<<<NB_U + NB_E, 512, 0, stream>>>(binE, cntE, binU, cntU, rowptr);

    // ---- 2 hops, double-buffered bf16 entity state ----
    agg_kernel<<<NB_U + NB_E, 512, 0, stream>>>(
        (const uint2*)curA, weight, binE, binU, rowptr,
        curB, out_entity, out_user);
    agg_kernel<<<NB_U + NB_E, 512, 0, stream>>>(
        (const uint2*)curB, weight, binE, binU, rowptr,
        curA, out_entity, out_user);
}

// Round 6
// 522.070 us; speedup vs baseline: 2.1240x; 1.0548x over previous
//
#include <hip/hip_runtime.h>

#define N_USERS 50000
#define N_ENTITIES 100000
#define N_RELATIONS 16
#define N_EDGES 3200000
#define NNZ 2500000
#define CH 64

#define RPB 64
#define NB_E 1563                 // ceil(N_ENTITIES/64) fine buckets
#define NB_U 782                  // ceil(N_USERS/64)
#define NBUCKETS (NB_E + NB_U)    // 2345
#define STAGE 3840                // sort LDS staging capacity (max bucket ~3400)

#define NCE 49                    // entity coarse buckets (2048 rows each)
#define NCU 25                    // user coarse buckets (2048 rows each)
#define CAPC_E 67072              // mean 65536, +~6 sigma
#define CAPC_U 104448             // mean 102400, +~6 sigma
#define NCU_DOUT 14               // user coarse buckets hosted in d_out scratch

#define PA_KG 256                 // pass-A KG blocks
#define PA_U  192                 // pass-A user blocks
#define SE 10                     // pass-B sub-blocks per entity coarse bucket
#define SU 16                     // pass-B sub-blocks per user coarse bucket

__device__ __forceinline__ unsigned short f2bf(float f) {
    unsigned u = __float_as_uint(f);
    u += 0x7FFF + ((u >> 16) & 1);   // round-to-nearest-even
    return (unsigned short)(u >> 16);
}

__device__ __forceinline__ int wave_incl_scan(int v, int lane) {
    int s = v;
    #pragma unroll
    for (int d = 1; d < 64; d <<= 1) {
        int x = __shfl_up(s, d, 64);
        if (lane >= d) s += x;
    }
    return s;
}

// ---------------------------------------------------------------------------
// Pass A: coarse partition (2048-row buckets). Per-block runs are 2-8KB with
// only 49/25 concurrent line-tails per block -> ~1x write amplification.
// Also accumulates EXACT per-fine-bucket counts (for CSR, kills CAP slack
// and the old reservation contention). Payload carries fine-within-coarse
// in bits 27-31; downstream field extraction (&0x1FFFF, >>17&15, >>rsh&63)
// is unaffected.
// Entity coarse bins live in d_out (scratch until init); user coarse bins
// split d_out tail + ws.
// ---------------------------------------------------------------------------
__global__ void __launch_bounds__(1024)
passA_kernel(const int* __restrict__ head, const int* __restrict__ tail,
             const int* __restrict__ type, const float* __restrict__ maskp,
             const int* __restrict__ irows, const int* __restrict__ icols,
             const float* __restrict__ ivals,
             int* __restrict__ fineCnt, int* __restrict__ cCurE,
             int* __restrict__ cCurU,
             int2* __restrict__ cbE, int2* __restrict__ cbU_d,
             int2* __restrict__ cbU_w) {
    __shared__ int histF[NB_E];
    __shared__ int histC[64];
    __shared__ int lbase[64];
    __shared__ int2* utab[NCU];
    const int blk = blockIdx.x;
    const int t = threadIdx.x;

    if (blk < PA_KG) {
        // ---- KG edges ----
        for (int i = t; i < NB_E; i += 1024) histF[i] = 0;
        if (t < NCE) histC[t] = 0;
        __syncthreads();
        const int chunk = (N_EDGES + PA_KG - 1) / PA_KG;
        int base = blk * chunk, lim = min(base + chunk, N_EDGES);
        for (int i = base + t; i < lim; i += 1024) {
            int h = head[i];
            atomicAdd(&histF[h >> 6], 1);
            atomicAdd(&histC[h >> 11], 1);
        }
        __syncthreads();
        for (int i = t; i < NB_E; i += 1024)
            if (histF[i]) atomicAdd(&fineCnt[NB_U + i], histF[i]);
        if (t < NCE) {
            int c = histC[t];
            lbase[t] = c ? atomicAdd(&cCurE[t], c) : 0;
            histC[t] = 0;
        }
        __syncthreads();
        int i = base + t;
        for (; i + 3072 < lim; i += 4096) {
            int i0 = i, i1 = i + 1024, i2 = i + 2048, i3 = i + 3072;
            int h0 = head[i0], h1 = head[i1], h2 = head[i2], h3 = head[i3];
            int x0 = tail[i0] | ((type[i0] - 1) << 17) | ((h0 & 63) << 21) | (((h0 >> 6) & 31) << 27);
            int x1 = tail[i1] | ((type[i1] - 1) << 17) | ((h1 & 63) << 21) | (((h1 >> 6) & 31) << 27);
            int x2 = tail[i2] | ((type[i2] - 1) << 17) | ((h2 & 63) << 21) | (((h2 >> 6) & 31) << 27);
            int x3 = tail[i3] | ((type[i3] - 1) << 17) | ((h3 & 63) << 21) | (((h3 >> 6) & 31) << 27);
            float m0 = maskp[i0], m1 = maskp[i1], m2 = maskp[i2], m3 = maskp[i3];
            int c0 = h0 >> 11, c1 = h1 >> 11, c2 = h2 >> 11, c3 = h3 >> 11;
            int l0 = lbase[c0] + atomicAdd(&histC[c0], 1);
            int l1 = lbase[c1] + atomicAdd(&histC[c1], 1);
            int l2 = lbase[c2] + atomicAdd(&histC[c2], 1);
            int l3 = lbase[c3] + atomicAdd(&histC[c3], 1);
            if (l0 < CAPC_E) cbE[(size_t)c0 * CAPC_E + l0] = make_int2(x0, __float_as_int(m0));
            if (l1 < CAPC_E) cbE[(size_t)c1 * CAPC_E + l1] = make_int2(x1, __float_as_int(m1));
            if (l2 < CAPC_E) cbE[(size_t)c2 * CAPC_E + l2] = make_int2(x2, __float_as_int(m2));
            if (l3 < CAPC_E) cbE[(size_t)c3 * CAPC_E + l3] = make_int2(x3, __float_as_int(m3));
        }
        for (; i < lim; i += 1024) {
            int h = head[i];
            int x = tail[i] | ((type[i] - 1) << 17) | ((h & 63) << 21) | (((h >> 6) & 31) << 27);
            int c = h >> 11;
            int loc = lbase[c] + atomicAdd(&histC[c], 1);
            if (loc < CAPC_E)
                cbE[(size_t)c * CAPC_E + loc] = make_int2(x, __float_as_int(maskp[i]));
        }
    } else {
        // ---- user interactions ----
        if (t < NCU)
            utab[t] = (t < NCU_DOUT) ? (cbU_d + (size_t)t * CAPC_U)
                                     : (cbU_w + (size_t)(t - NCU_DOUT) * CAPC_U);
        for (int i = t; i < NB_U; i += 1024) histF[i] = 0;
        if (t < NCU) histC[t] = 0;
        __syncthreads();
        const int ub = blk - PA_KG;
        const int chunk = (NNZ + PA_U - 1) / PA_U;
        int base = ub * chunk, lim = min(base + chunk, NNZ);
        for (int i = base + t; i < lim; i += 1024) {
            int r = irows[i];
            atomicAdd(&histF[r >> 6], 1);
            atomicAdd(&histC[r >> 11], 1);
        }
        __syncthreads();
        for (int i = t; i < NB_U; i += 1024)
            if (histF[i]) atomicAdd(&fineCnt[i], histF[i]);
        if (t < NCU) {
            int c = histC[t];
            lbase[t] = c ? atomicAdd(&cCurU[t], c) : 0;
            histC[t] = 0;
        }
        __syncthreads();
        int i = base + t;
        for (; i + 3072 < lim; i += 4096) {
            int i0 = i, i1 = i + 1024, i2 = i + 2048, i3 = i + 3072;
            int r0 = irows[i0], r1 = irows[i1], r2 = irows[i2], r3 = irows[i3];
            int x0 = icols[i0] | ((r0 & 63) << 17) | (((r0 >> 6) & 31) << 27);
            int x1 = icols[i1] | ((r1 & 63) << 17) | (((r1 >> 6) & 31) << 27);
            int x2 = icols[i2] | ((r2 & 63) << 17) | (((r2 >> 6) & 31) << 27);
            int x3 = icols[i3] | ((r3 & 63) << 17) | (((r3 >> 6) & 31) << 27);
            float v0 = ivals[i0], v1 = ivals[i1], v2 = ivals[i2], v3 = ivals[i3];
            int c0 = r0 >> 11, c1 = r1 >> 11, c2 = r2 >> 11, c3 = r3 >> 11;
            int l0 = lbase[c0] + atomicAdd(&histC[c0], 1);
            int l1 = lbase[c1] + atomicAdd(&histC[c1], 1);
            int l2 = lbase[c2] + atomicAdd(&histC[c2], 1);
            int l3 = lbase[c3] + atomicAdd(&histC[c3], 1);
            if (l0 < CAPC_U) utab[c0][l0] = make_int2(x0, __float_as_int(v0));
            if (l1 < CAPC_U) utab[c1][l1] = make_int2(x1, __float_as_int(v1));
            if (l2 < CAPC_U) utab[c2][l2] = make_int2(x2, __float_as_int(v2));
            if (l3 < CAPC_U) utab[c3][l3] = make_int2(x3, __float_as_int(v3));
        }
        for (; i < lim; i += 1024) {
            int r = irows[i];
            int x = icols[i] | ((r & 63) << 17) | (((r >> 6) & 31) << 27);
            int c = r >> 11;
            int loc = lbase[c] + atomicAdd(&histC[c], 1);
            if (loc < CAPC_U) utab[c][loc] = make_int2(x, __float_as_int(ivals[i]));
        }
    }
}

// ---------------------------------------------------------------------------
// Scan: exclusive prefix over the 2345 exact fine-bucket counts ->
// fineBase (CSR bases, kept for sort/agg) and fineCur (pass-B cursors).
// ---------------------------------------------------------------------------
__global__ void __launch_bounds__(512)
scan_kernel(const int* __restrict__ fineCnt, int* __restrict__ fineBase,
            int* __restrict__ fineCur) {
    __shared__ int wsums[8];
    __shared__ int carry_s;
    const int t = threadIdx.x, w = t >> 6, lane = t & 63;
    if (t == 0) carry_s = 0;
    __syncthreads();
    for (int base = 0; base < NBUCKETS; base += 512) {
        int i = base + t;
        int v = (i < NBUCKETS) ? fineCnt[i] : 0;
        int s = wave_incl_scan(v, lane);
        if (lane == 63) wsums[w] = s;
        __syncthreads();
        int carry = carry_s;
        if (w == 0) {
            int ws = (lane < 8) ? wsums[lane] : 0;
            int ss = wave_incl_scan(ws, lane);
            if (lane < 8) wsums[lane] = ss - ws;
        }
        __syncthreads();
        int excl = s - v + wsums[w] + carry;
        if (i < NBUCKETS) { fineBase[i] = excl; fineCur[i] = excl; }
        __syncthreads();
        if (t == 511) carry_s = excl + v;
        __syncthreads();
    }
}

// ---------------------------------------------------------------------------
// Pass B: fine partition. Each block handles a slice of one coarse bucket
// and scatters into its <=32 fine buckets (exact CSR slots). Only 32
// concurrent line-tails per block -> ~1x write amplification.
// ---------------------------------------------------------------------------
__global__ void __launch_bounds__(1024)
passB_kernel(const int* __restrict__ cCurE, const int* __restrict__ cCurU,
             const int2* __restrict__ cbE, const int2* __restrict__ cbU_d,
             const int2* __restrict__ cbU_w,
             int* __restrict__ fineCur, int2* __restrict__ binAll) {
    __shared__ int h32[32];
    __shared__ int lb[32];
    const int blk = blockIdx.x, t = threadIdx.x;
    const int2* __restrict__ src;
    int cnt, sub, S, fid0;
    if (blk < NCE * SE) {
        int c = blk / SE; sub = blk % SE; S = SE;
        cnt = min(cCurE[c], CAPC_E);
        src = cbE + (size_t)c * CAPC_E;
        fid0 = NB_U + c * 32;
    } else {
        int c = (blk - NCE * SE) / SU; sub = (blk - NCE * SE) % SU; S = SU;
        cnt = min(cCurU[c], CAPC_U);
        src = (c < NCU_DOUT) ? cbU_d + (size_t)c * CAPC_U
                             : cbU_w + (size_t)(c - NCU_DOUT) * CAPC_U;
        fid0 = c * 32;
    }
    int len = (cnt + S - 1) / S;
    int b0 = sub * len, b1 = min(b0 + len, cnt);
    if (t < 32) h32[t] = 0;
    __syncthreads();
    for (int i = b0 + t; i < b1; i += 1024)
        atomicAdd(&h32[(src[i].x >> 27) & 31], 1);
    __syncthreads();
    if (t < 32) {
        int c2 = h32[t];
        lb[t] = c2 ? atomicAdd(&fineCur[fid0 + t], c2) : 0;
        h32[t] = 0;
    }
    __syncthreads();
    int i = b0 + t;
    for (; i + 3072 < b1; i += 4096) {
        int2 e0 = src[i], e1 = src[i + 1024], e2 = src[i + 2048], e3 = src[i + 3072];
        int f0 = (e0.x >> 27) & 31, f1 = (e1.x >> 27) & 31;
        int f2 = (e2.x >> 27) & 31, f3 = (e3.x >> 27) & 31;
        int l0 = lb[f0] + atomicAdd(&h32[f0], 1);
        int l1 = lb[f1] + atomicAdd(&h32[f1], 1);
        int l2 = lb[f2] + atomicAdd(&h32[f2], 1);
        int l3 = lb[f3] + atomicAdd(&h32[f3], 1);
        binAll[l0] = e0; binAll[l1] = e1; binAll[l2] = e2; binAll[l3] = e3;
    }
    for (; i < b1; i += 1024) {
        int2 e = src[i];
        int f = (e.x >> 27) & 31;
        binAll[lb[f] + atomicAdd(&h32[f], 1)] = e;
    }
}

// ---------------------------------------------------------------------------
// Sort+init: blocks [0,2345) counting-sort each exact-CSR bucket by rowlocal
// in LDS (in place) and emit absolute rowptr[65]; blocks >=2345 do the init
// copy (residuals fp32 + bf16 entity state). Init runs here (after pass B)
// because d_out doubled as coarse-bin scratch until now.
// ---------------------------------------------------------------------------
__global__ void __launch_bounds__(512)
sortinit_kernel(int2* __restrict__ binAll, const int* __restrict__ fineCnt,
                const int* __restrict__ fineBase, int* __restrict__ rowptr,
                const float4* __restrict__ user_emb,
                const float4* __restrict__ entity_emb,
                ushort4* __restrict__ cur_bf,
                float4* __restrict__ out_entity, float4* __restrict__ out_user) {
    __shared__ int2 buf[STAGE];       // 30720 B
    __shared__ int2 sbuf[STAGE];      // 30720 B
    __shared__ int  hist[RPB];
    __shared__ int  offs[RPB + 1];

    const int blk = blockIdx.x;
    const int t = threadIdx.x;
    if (blk >= NBUCKETS) {
        const int ne4 = N_ENTITIES * CH / 4;
        const int nu4 = N_USERS * CH / 4;
        int i = (blk - NBUCKETS) * 512 + t;
        if (i < ne4) {
            float4 v = entity_emb[i];
            out_entity[i] = v;
            ushort4 bq;
            bq.x = f2bf(v.x); bq.y = f2bf(v.y); bq.z = f2bf(v.z); bq.w = f2bf(v.w);
            cur_bf[i] = bq;
        }
        if (i < nu4) out_user[i] = user_emb[i];
        return;
    }

    const int b = blk;
    const bool is_user = (b < NB_U);
    const int base = fineBase[b];
    int2* __restrict__ bin = binAll + base;
    const int cnt = min(fineCnt[b], STAGE);
    const int rsh = is_user ? 17 : 21;

    if (t < RPB) hist[t] = 0;
    for (int i = t; i < cnt; i += 512) buf[i] = bin[i];
    __syncthreads();
    for (int i = t; i < cnt; i += 512)
        atomicAdd(&hist[(buf[i].x >> rsh) & 63], 1);
    __syncthreads();
    if (t < 64) {
        int v = hist[t];
        int s = wave_incl_scan(v, t);
        offs[t] = s - v;
        if (t == 63) offs[64] = s;
    }
    __syncthreads();
    if (t < RPB) hist[t] = 0;        // becomes cursor
    __syncthreads();
    for (int i = t; i < cnt; i += 512) {
        int2 p = buf[i];
        int r = (p.x >> rsh) & 63;
        int k = atomicAdd(&hist[r], 1);
        sbuf[offs[r] + k] = p;
    }
    __syncthreads();
    for (int i = t; i < cnt; i += 512) bin[i] = sbuf[i];   // coalesced writeback
    if (t <= 64) rowptr[b * 65 + t] = base + offs[t];      // absolute offsets
}

// ---------------------------------------------------------------------------
// Aggregation (v7 geometry, exact CSR): one block (8 waves) per bucket;
// wave w owns rows 8w..8w+7; 16 lanes/edge, uint2 = 4 packed bf16 channels,
// 8-edge unroll. Absolute rowptr into the single binAll array. Per-row
// fused epilogue: merge 4 groups, L2-normalize, residual (+ next state).
// ---------------------------------------------------------------------------
__global__ void __launch_bounds__(512)
agg_kernel(const uint2* __restrict__ cur64,    // bf16 quads, 16 uint2/row
           const float* __restrict__ weight,
           const int2* __restrict__ binAll, const int* __restrict__ rowptr,
           unsigned short* __restrict__ nxt,
           float* __restrict__ res_e, float* __restrict__ res_u) {
    __shared__ float4 wl4[N_RELATIONS * 16];   // 4 KB
    __shared__ int    srp[RPB + 1];

    const int b = blockIdx.x;
    const int t = threadIdx.x;
    const int w = t >> 6;        // wave 0..7
    const int lane = t & 63;
    const int g = lane >> 4;     // edge-group 0..3
    const int c2 = lane & 15;    // uint2 index within row (4 channels)
    const bool is_user = (b < NB_U);
    const int eb = b - NB_U;

    if (!is_user)
        for (int i = t; i < N_RELATIONS * 16; i += 512)
            wl4[i] = ((const float4*)weight)[i];
    if (t < RPB + 1) srp[t] = rowptr[b * 65 + t];
    __syncthreads();

    #pragma unroll
    for (int rr = 0; rr < 8; ++rr) {
        const int row = (w << 3) + rr;
        const int s = srp[row], e = srp[row + 1];
        float x0 = 0.f, x1 = 0.f, x2 = 0.f, x3 = 0.f;
        int i = s;
        if (is_user) {
            for (; i + 7 < e; i += 8) {
                int2 pa = binAll[i + g];
                int2 pb = binAll[i + 4 + g];
                uint2 qa = cur64[(size_t)(pa.x & 0x1FFFF) * 16 + c2];
                uint2 qb = cur64[(size_t)(pb.x & 0x1FFFF) * 16 + c2];
                float sa = __int_as_float(pa.y);
                float sb = __int_as_float(pb.y);
                x0 += __uint_as_float(qa.x << 16) * sa;
                x1 += __uint_as_float(qa.x & 0xFFFF0000u) * sa;
                x2 += __uint_as_float(qa.y << 16) * sa;
                x3 += __uint_as_float(qa.y & 0xFFFF0000u) * sa;
                x0 += __uint_as_float(qb.x << 16) * sb;
                x1 += __uint_as_float(qb.x & 0xFFFF0000u) * sb;
                x2 += __uint_as_float(qb.y << 16) * sb;
                x3 += __uint_as_float(qb.y & 0xFFFF0000u) * sb;
            }
            for (; i < e; i += 4) {          // masked 4-edge tail
                int idx = i + g;
                bool vld = idx < e;
                int2 p = binAll[vld ? idx : i];
                uint2 q = cur64[(size_t)(p.x & 0x1FFFF) * 16 + c2];
                float sv = vld ? __int_as_float(p.y) : 0.f;
                x0 += __uint_as_float(q.x << 16) * sv;
                x1 += __uint_as_float(q.x & 0xFFFF0000u) * sv;
                x2 += __uint_as_float(q.y << 16) * sv;
                x3 += __uint_as_float(q.y & 0xFFFF0000u) * sv;
            }
        } else {
            for (; i + 7 < e; i += 8) {
                int2 pa = binAll[i + g];
                int2 pb = binAll[i + 4 + g];
                uint2 qa = cur64[(size_t)(pa.x & 0x1FFFF) * 16 + c2];
                uint2 qb = cur64[(size_t)(pb.x & 0x1FFFF) * 16 + c2];
                float4 wa = wl4[((pa.x >> 17) & 15) * 16 + c2];
                float4 wb = wl4[((pb.x >> 17) & 15) * 16 + c2];
                float sa = __int_as_float(pa.y);
                float sb = __int_as_float(pb.y);
                x0 += __uint_as_float(qa.x << 16) * (sa * wa.x);
                x1 += __uint_as_float(qa.x & 0xFFFF0000u) * (sa * wa.y);
                x2 += __uint_as_float(qa.y << 16) * (sa * wa.z);
                x3 += __uint_as_float(qa.y & 0xFFFF0000u) * (sa * wa.w);
                x0 += __uint_as_float(qb.x << 16) * (sb * wb.x);
                x1 += __uint_as_float(qb.x & 0xFFFF0000u) * (sb * wb.y);
                x2 += __uint_as_float(qb.y << 16) * (sb * wb.z);
                x3 += __uint_as_float(qb.y & 0xFFFF0000u) * (sb * wb.w);
            }
            for (; i < e; i += 4) {
                int idx = i + g;
                bool vld = idx < e;
                int2 p = binAll[vld ? idx : i];
                uint2 q = cur64[(size_t)(p.x & 0x1FFFF) * 16 + c2];
                float4 wv = wl4[((p.x >> 17) & 15) * 16 + c2];
                float sv = vld ? __int_as_float(p.y) : 0.f;
                x0 += __uint_as_float(q.x << 16) * (sv * wv.x);
                x1 += __uint_as_float(q.x & 0xFFFF0000u) * (sv * wv.y);
                x2 += __uint_as_float(q.y << 16) * (sv * wv.z);
                x3 += __uint_as_float(q.y & 0xFFFF0000u) * (sv * wv.w);
            }
        }

        // merge the 4 edge-groups
        x0 += __shfl_xor(x0, 16, 64); x0 += __shfl_xor(x0, 32, 64);
        x1 += __shfl_xor(x1, 16, 64); x1 += __shfl_xor(x1, 32, 64);
        x2 += __shfl_xor(x2, 16, 64); x2 += __shfl_xor(x2, 32, 64);
        x3 += __shfl_xor(x3, 16, 64); x3 += __shfl_xor(x3, 32, 64);
        float ss = x0 * x0 + x1 * x1 + x2 * x2 + x3 * x3;
        #pragma unroll
        for (int o = 8; o; o >>= 1) ss += __shfl_xor(ss, o, 64);
        float inv = 1.f / fmaxf(sqrtf(ss), 1e-12f);
        float y0 = x0 * inv, y1 = x1 * inv, y2 = x2 * inv, y3 = x3 * inv;
        if (g == 0) {    // lanes 0-15 hold the complete row; 16B stores
            if (is_user) {
                int grow = b * RPB + row;
                if (grow < N_USERS) {
                    float4* p = (float4*)res_u + (size_t)grow * 16 + c2;
                    float4 v = *p;
                    v.x += y0; v.y += y1; v.z += y2; v.w += y3;
                    *p = v;
                }
            } else {
                int grow = eb * RPB + row;
                if (grow < N_ENTITIES) {
                    uint2 pk;
                    pk.x = (unsigned)f2bf(y0) | ((unsigned)f2bf(y1) << 16);
                    pk.y = (unsigned)f2bf(y2) | ((unsigned)f2bf(y3) << 16);
                    ((uint2*)nxt)[(size_t)grow * 16 + c2] = pk;
                    float4* p = (float4*)res_e + (size_t)grow * 16 + c2;
                    float4 v = *p;
                    v.x += y0; v.y += y1; v.z += y2; v.w += y3;
                    *p = v;
                }
            }
        }
    }
}

extern "C" void kernel_launch(void* const* d_in, const int* in_sizes, int n_in,
                              void* d_out, int out_size, void* d_ws, size_t ws_size,
                              hipStream_t stream) {
    const float* user_emb   = (const float*)d_in[0];
    const float* entity_emb = (const float*)d_in[1];
    const float* weight     = (const float*)d_in[2];
    const float* mask       = (const float*)d_in[3];
    const float* ivals      = (const float*)d_in[4];
    const int*   edge_head  = (const int*)d_in[5];
    const int*   edge_tail  = (const int*)d_in[6];
    const int*   edge_type  = (const int*)d_in[7];
    const int*   irows      = (const int*)d_in[8];
    const int*   icols      = (const int*)d_in[9];

    float* out_entity = (float*)d_out;
    float* out_user   = (float*)d_out + (size_t)N_ENTITIES * CH;

    // ---- d_out doubles as coarse-bin scratch until sortinit rewrites it ----
    int2* cbE   = (int2*)d_out;                          // 49*67072*8 = 26.29 MB
    int2* cbU_d = cbE + (size_t)NCE * CAPC_E;            // 14*104448*8 = 11.70 MB

    // ---- workspace layout (total ~81.0 MB) ----
    unsigned short* curA = (unsigned short*)d_ws;                    // 12.8 MB
    unsigned short* curB = curA + (size_t)N_ENTITIES * CH;           // 12.8 MB
    int2* binAll = (int2*)(curB + (size_t)N_ENTITIES * CH);          // 45.6 MB
    int2* cbU_w  = binAll + (size_t)(N_EDGES + NNZ);                 // 9.19 MB
    int*  fineCnt  = (int*)(cbU_w + (size_t)(NCU - NCU_DOUT) * CAPC_U);
    int*  cCurE    = fineCnt + NBUCKETS;                             // 49
    int*  cCurU    = cCurE + NCE;                                    // 25
    int*  fineBase = cCurU + NCU;                                    // 2345
    int*  fineCur  = fineBase + NBUCKETS;                            // 2345
    int*  rowptr   = fineCur + NBUCKETS;                             // 2345*65

    hipMemsetAsync(fineCnt, 0, (size_t)(NBUCKETS + NCE + NCU) * sizeof(int), stream);

    // ---- pass A: coarse partition + exact fine counts ----
    passA_kernel<<<PA_KG + PA_U, 1024, 0, stream>>>(
        edge_head, edge_tail, edge_type, mask, irows, icols, ivals,
        fineCnt, cCurE, cCurU, cbE, cbU_d, cbU_w);

    // ---- exclusive scan -> exact CSR bases + pass-B cursors ----
    scan_kernel<<<1, 512, 0, stream>>>(fineCnt, fineBase, fineCur);

    // ---- pass B: fine partition into exact CSR ----
    passB_kernel<<<NCE * SE + NCU * SU, 1024, 0, stream>>>(
        cCurE, cCurU, cbE, cbU_d, cbU_w, fineCur, binAll);

    // ---- sort buckets by rowlocal + init (coarse bins dead; d_out reusable) ----
    {
        const int init_blocks = (N_ENTITIES * CH / 4 + 511) / 512;   // 3125
        sortinit_kernel<<<NBUCKETS + init_blocks, 512, 0, stream>>>(
            binAll, fineCnt, fineBase, rowptr,
            (const float4*)user_emb, (const float4*)entity_emb,
            (ushort4*)curA, (float4*)out_entity, (float4*)out_user);
    }

    // ---- 2 hops, double-buffered bf16 entity state ----
    agg_kernel<<<NBUCKETS, 512, 0, stream>>>(
        (const uint2*)curA, weight, binAll, rowptr,
        curB, out_entity, out_user);
    agg_kernel<<<NBUCKETS, 512, 0, stream>>>(
        (const uint2*)curB, weight, binAll, rowptr,
        curA, out_entity, out_user);
}